// Round 14
// baseline (158.885 us; speedup 1.0000x reference)
//
#include <hip/hip_runtime.h>
#include <stdint.h>

#define DIN 1024
#define DIMM 1024
#define NH 16
#define HD 64
#define SEQ 2048
#define BATCH 2
#define MTOT (BATCH*SEQ)   // 4096
#define SCALE 0.125f       // 1/sqrt(64)

typedef __bf16 bf16;
typedef __bf16 bf16x8 __attribute__((ext_vector_type(8)));
typedef __bf16 bf16x4 __attribute__((ext_vector_type(4)));
typedef float f32x4 __attribute__((ext_vector_type(4)));

// async global->LDS, 16B per lane (HW: wave-uniform LDS base + lane*16).
// Staged tiles use an XOR swizzle: LDS slot (row, c8) holds global col-group
// c8 ^ (row & 7); readers XOR their col-group by (row & 7). Spreads stride-64
// fragment reads across all 32 banks with zero padding.
__device__ __forceinline__ void async16(bf16* lds, const bf16* g) {
  __builtin_amdgcn_global_load_lds(
      (const __attribute__((address_space(1))) void*)g,
      (__attribute__((address_space(3))) void*)lds, 16, 0, 0);
}

#define WAIT_VM(n)  asm volatile("s_waitcnt vmcnt(" #n ")" ::: "memory")
#define BARRIER()   asm volatile("s_barrier" ::: "memory")

// ---------------- fp32 -> bf16 convert: x (4M) + wq|wk|wv|wo (4M) ----------
__global__ __launch_bounds__(256) void convert_all(const float* __restrict__ x,
                                                   const float* __restrict__ wq,
                                                   const float* __restrict__ wk,
                                                   const float* __restrict__ wv,
                                                   const float* __restrict__ wo,
                                                   bf16* __restrict__ xb,
                                                   bf16* __restrict__ Wb) {
  const int t = blockIdx.x * 256 + threadIdx.x;
#pragma unroll
  for (int i = 0; i < 4; ++i) {
    const int c = t + i * 262144;   // 8-elem chunk id, total 1048576
    const float* src;
    bf16* dst;
    if (c < 524288) {               // x: 4M elems
      src = x + (size_t)c * 8;
      dst = xb + (size_t)c * 8;
    } else {
      const int cw = c - 524288;
      const int w = cw >> 17;       // 131072 chunks per weight
      const int off = (cw & 131071) * 8;
      const float* wp = (w == 0) ? wq : (w == 1) ? wk : (w == 2) ? wv : wo;
      src = wp + off;
      dst = Wb + (size_t)w * 1048576 + off;
    }
    f32x4 a = *(const f32x4*)src;
    f32x4 b = *(const f32x4*)(src + 4);
    bf16x8 r;
    r[0] = (bf16)a[0]; r[1] = (bf16)a[1]; r[2] = (bf16)a[2]; r[3] = (bf16)a[3];
    r[4] = (bf16)b[0]; r[5] = (bf16)b[1]; r[6] = (bf16)b[2]; r[7] = (bf16)b[3];
    *(bf16x8*)dst = r;
  }
}

// ---------------- QKV GEMM v5: 128x192 tile, 2 blocks/CU, counted vmcnt ---
// Q region written PRE-SCALED by C1 = SCALE*log2(e) so attn softmax is
// p = exp2(s) directly. Vt is written with a k-PERMUTATION within each
// 32-col group (k' = quad*8 + b*4 + r): PV's B-fragment (P, packed at
// j=b*4+r from original k=16b+4quad+r) then matches a CONTIGUOUS 16B
// A-fragment read of V -> attn's V reads become conflict-free b128 at the
// same swizzled col-groups as K.
__global__ __launch_bounds__(256, 2) void qkv_gemm(const bf16* __restrict__ A,
                                                   const bf16* __restrict__ B,
                                                   bf16* __restrict__ Q,
                                                   bf16* __restrict__ Kb,
                                                   bf16* __restrict__ Vt) {
  __shared__ bf16 As0[128 * 64];   // 16 KB
  __shared__ bf16 As1[128 * 64];
  __shared__ bf16 Bs0[192 * 64];   // 24 KB
  __shared__ bf16 Bs1[192 * 64];
  const int tid  = threadIdx.x;
  const int lane = tid & 63;
  const int wave = tid >> 6;
  const int lrow = lane & 15;
  const int quad = lane >> 4;
  const int wrow = wave >> 1;            // 0..1 -> 64-row band
  const int wcol = wave & 1;             // 0..1 -> 96-col band
  const int lin  = blockIdx.x;           // 0..511
  const int xcd  = lin & 7;
  const int idx  = lin >> 3;             // 0..63
  const int nbase = (xcd * 2 + (idx & 1)) * 192;  // 16 N-tiles, 2 per XCD
  const int mbase = (idx >> 1) * 128;             // 32 M-tiles

  // staging: 256 thr cover 32 rows x 128 B per pass; lane->lane*16B in LDS
  const int srow = tid >> 3;             // 0..31
  const int sdst = srow * 64 + (tid & 7) * 8;      // LDS dest (elems)
  const int sx   = ((tid & 7) ^ (srow & 7)) * 8;   // swizzled global col

  const bf16* ap = A + (size_t)(mbase + srow) * DIN + sx;
  const bf16* bp = B + (size_t)(nbase + srow) * DIN + sx;

  f32x4 acc[4][6] = {};

#define QKV_STAGE(Asb, Bsb)                                          \
  do {                                                               \
    _Pragma("unroll")                                                \
    for (int i = 0; i < 4; ++i)                                      \
      async16(&Asb[sdst + i * 2048], ap + (size_t)i * 32 * DIN);     \
    _Pragma("unroll")                                                \
    for (int i = 0; i < 6; ++i)                                      \
      async16(&Bsb[sdst + i * 2048], bp + (size_t)i * 32 * DIN);     \
  } while (0)

#define QKV_COMPUTE(Asb, Bsb)                                        \
  do {                                                               \
    __builtin_amdgcn_s_setprio(1);                                   \
    _Pragma("unroll")                                                \
    for (int h = 0; h < 2; ++h) {                                    \
      const int cx = ((h * 4 + quad) ^ (lrow & 7)) * 8;              \
      bf16x8 af[4], bfr[6];                                          \
      _Pragma("unroll")                                              \
      for (int i = 0; i < 4; ++i)                                    \
        af[i] = *(const bf16x8*)&Asb[(wrow * 64 + i * 16 + lrow) * 64 + cx]; \
      _Pragma("unroll")                                              \
      for (int j = 0; j < 6; ++j)                                    \
        bfr[j] = *(const bf16x8*)&Bsb[(wcol * 96 + j * 16 + lrow) * 64 + cx]; \
      _Pragma("unroll")                                              \
      for (int i = 0; i < 4; ++i)                                    \
        _Pragma("unroll")                                            \
        for (int j = 0; j < 6; ++j)                                  \
          acc[i][j] = __builtin_amdgcn_mfma_f32_16x16x32_bf16(af[i], bfr[j], acc[i][j], 0, 0, 0); \
    }                                                                \
    __builtin_amdgcn_s_setprio(0);                                   \
  } while (0)

  // prologue: stage K-step 0 into buf0; full drain (only these 10 in flight)
  QKV_STAGE(As0, Bs0);
  WAIT_VM(0);
  BARRIER();

  // 16 K-steps, unrolled x2 for compile-time buffer selection.
#pragma unroll 1
  for (int t = 0; t < 16; t += 2) {
    // ---- even step: compute buf0, stage t+1 into buf1 ----
    ap += 64; bp += 64;
    QKV_STAGE(As1, Bs1);
    WAIT_VM(10);         // own buf0 loads done; buf1's 10 stay in flight
    BARRIER();           // all waves: buf0 fully landed
    QKV_COMPUTE(As0, Bs0);
    BARRIER();           // all reads of buf0 done before its next overwrite
    // ---- odd step: compute buf1, stage t+2 into buf0 ----
    if (t + 2 < 16) {
      ap += 64; bp += 64;
      QKV_STAGE(As0, Bs0);
      WAIT_VM(10);       // own buf1 loads done
    } else {
      WAIT_VM(0);
    }
    BARRIER();
    QKV_COMPUTE(As1, Bs1);
    BARRIER();
  }

#undef QKV_STAGE
#undef QKV_COMPUTE

  // ---- epilogue: region-split C write (Q pre-scaled; Vt k-permuted) ----
  const float C1 = 0.18033688f;          // SCALE * log2(e)
#pragma unroll
  for (int mt = 0; mt < 4; ++mt) {
    const int m0 = mbase + wrow * 64 + mt * 16 + quad * 4;
#pragma unroll
    for (int nt = 0; nt < 6; ++nt) {
      const int n16 = nbase + wcol * 96 + nt * 16;  // 16-aligned; frag-uniform
      const int n = n16 + lrow;
      if (n16 < 1024) {
#pragma unroll
        for (int rr = 0; rr < 4; ++rr)
          Q[(size_t)(m0 + rr) * 1024 + n] = (bf16)(acc[mt][nt][rr] * C1);
      } else if (n16 < 2048) {
#pragma unroll
        for (int rr = 0; rr < 4; ++rr)
          Kb[(size_t)(m0 + rr) * 1024 + (n - 1024)] = (bf16)acc[mt][nt][rr];
      } else {
        const int nn = n - 2048;
        const int row = ((m0 >> 11) * 16 + (nn >> 6)) * 64 + (nn & 63);
        const int kb  = m0 & 2047;       // original k (seq within batch)
        const int colp = (kb & ~31) | (quad * 8) | ((mt & 1) * 4);  // k-perm
        bf16x4 ov;
#pragma unroll
        for (int rr = 0; rr < 4; ++rr) ov[rr] = (bf16)acc[mt][nt][rr];
        *(bf16x4*)&Vt[(size_t)row * SEQ + colp] = ov;
      }
    }
  }
}

// ---------------- proj GEMM v3: 128x32 tile, 4 blocks/CU, counted vmcnt ---
// proj was paying qkv-like convoy time for 1/3 the FLOPs (per-step convoy
// cost is ~independent of per-step work). Lever that has worked every time:
// MORE independent barrier domains. Tile 128x32 -> grid 32M x 32N = 1024
// blocks = 4/CU, LDS 40 KB (4x40 = 160 = full pool). 4 interleaved domains
// quadruple the convoy cover. XCD remap: 4 N-tiles per XCD (B cols stay
// L2-resident); A-panel re-reads absorbed by L2/L3.
__global__ __launch_bounds__(256, 4) void proj_gemm(const bf16* __restrict__ A,
                                                    const bf16* __restrict__ B,
                                                    float* __restrict__ C) {
  __shared__ bf16 As0[128 * 64];   // 16 KB
  __shared__ bf16 As1[128 * 64];
  __shared__ bf16 Bs0[32 * 64];    // 4 KB
  __shared__ bf16 Bs1[32 * 64];
  const int tid  = threadIdx.x;
  const int lane = tid & 63;
  const int wave = tid >> 6;
  const int lrow = lane & 15;
  const int quad = lane >> 4;
  const int wr = (wave >> 1) * 64;       // 2 M bands of 64
  const int wc = (wave & 1) * 16;        // 2 N bands of 16
  const int lin = blockIdx.x;            // 0..1023
  const int xcd = lin & 7;
  const int idx = lin >> 3;              // 0..127
  const int nbase = (xcd * 4 + (idx & 3)) * 32;  // 32 N-tiles, 4 per XCD
  const int mbase = (idx >> 2) * 128;            // 32 M-tiles
  const int srow = tid >> 3;
  const int sdst = srow * 64 + (tid & 7) * 8;
  const int sx   = ((tid & 7) ^ (srow & 7)) * 8;

  const bf16* ap = A + (size_t)(mbase + srow) * DIMM + sx;
  const bf16* bp = B + (size_t)(nbase + srow) * DIMM + sx;

  f32x4 acc[4] = {};

#define PRJ_STAGE(Asb, Bsb)                                          \
  do {                                                               \
    _Pragma("unroll")                                                \
    for (int i = 0; i < 4; ++i)                                      \
      async16(&Asb[sdst + i * 2048], ap + (size_t)i * 32 * DIMM);    \
    async16(&Bsb[sdst], bp);                                         \
  } while (0)

#define PRJ_COMPUTE(Asb, Bsb)                                        \
  do {                                                               \
    __builtin_amdgcn_s_setprio(1);                                   \
    _Pragma("unroll")                                                \
    for (int h = 0; h < 2; ++h) {                                    \
      const int cx = ((h * 4 + quad) ^ (lrow & 7)) * 8;              \
      bf16x8 af[4], bfr;                                             \
      _Pragma("unroll")                                              \
      for (int i = 0; i < 4; ++i)                                    \
        af[i] = *(const bf16x8*)&Asb[(wr + i * 16 + lrow) * 64 + cx]; \
      bfr = *(const bf16x8*)&Bsb[(wc + lrow) * 64 + cx];             \
      _Pragma("unroll")                                              \
      for (int mt = 0; mt < 4; ++mt)                                 \
        acc[mt] = __builtin_amdgcn_mfma_f32_16x16x32_bf16(af[mt], bfr, acc[mt], 0, 0, 0); \
    }                                                                \
    __builtin_amdgcn_s_setprio(0);                                   \
  } while (0)

  PRJ_STAGE(As0, Bs0);
  WAIT_VM(0);
  BARRIER();

#pragma unroll 1
  for (int t = 0; t < 16; t += 2) {
    ap += 64; bp += 64;
    PRJ_STAGE(As1, Bs1);
    WAIT_VM(5);
    BARRIER();
    PRJ_COMPUTE(As0, Bs0);
    BARRIER();
    if (t + 2 < 16) {
      ap += 64; bp += 64;
      PRJ_STAGE(As0, Bs0);
      WAIT_VM(5);
    } else {
      WAIT_VM(0);
    }
    BARRIER();
    PRJ_COMPUTE(As1, Bs1);
    BARRIER();
  }

#undef PRJ_STAGE
#undef PRJ_COMPUTE

#pragma unroll
  for (int mt = 0; mt < 4; ++mt) {
    const int m0 = mbase + wr + mt * 16 + quad * 4;
    const int n = nbase + wc + lrow;
#pragma unroll
    for (int rr = 0; rr < 4; ++rr)
      C[(size_t)(m0 + rr) * 1024 + n] = acc[mt][rr];
  }
}

// ---------------- Causal flash attention v6 (R10 session-best, verbatim) --
// 512 blocks, 2/CU, KVBLK=128, q-split waves (16 rows each), k-permuted Vt
// -> conflict-free b128 V reads, pairs (31-p, p) = exactly 17 iterations.
__global__ __launch_bounds__(256, 2) void attn(const bf16* __restrict__ Q,
                                               const bf16* __restrict__ K,
                                               const bf16* __restrict__ Vt,
                                               bf16* __restrict__ O) {
  __shared__ bf16 Ks[2][128 * 64];   // 16 KB each buf
  __shared__ bf16 Vts[2][128 * 64];  // 2 sub-tiles of [64][64] per buf
  const int tid  = threadIdx.x;
  const int wave = tid >> 6;
  const int lane = tid & 63;
  const int lrow = lane & 15;
  const int quad = lane >> 4;
  const int lin  = blockIdx.x;           // 0..511
  const int bh   = lin & 31;             // same bh -> same XCD residue (L2)
  const int pp   = lin >> 5;             // 0..15: pair id
  const int b = bh >> 4;
  const int h = bh & 15;

  const bf16* Qh  = Q  + (size_t)(b * SEQ) * DIMM + h * HD;
  const bf16* Kh  = K  + (size_t)(b * SEQ) * DIMM + h * HD;
  const bf16* Vth = Vt + (size_t)bh * 64 * SEQ;

  // staging coords: 256 thr cover 32 rows x 128B per pass; swizzled src col
  const int srow = tid >> 3;             // 0..31
  const int sdst = srow * 64 + (tid & 7) * 8;      // LDS dest (elems)
  const int sx   = ((tid & 7) ^ (srow & 7)) * 8;   // (srow+32)&7 == srow&7
  const int cx0 = ((0 + quad) ^ (lrow & 7)) * 8;
  const int cx1 = ((4 + quad) ^ (lrow & 7)) * 8;

  // stage one 128-row K tile + one 64x128 V tile (8 passes total)
#define ATT_STAGE(buf, kg, vg)                                        \
  do {                                                                \
    _Pragma("unroll")                                                 \
    for (int i = 0; i < 4; ++i)                                       \
      async16(&Ks[buf][sdst + i * 2048], kg + (size_t)i * 32 * DIMM); \
    async16(&Vts[buf][sdst],        vg);                              \
    async16(&Vts[buf][sdst + 2048], vg + (size_t)32 * SEQ);           \
    async16(&Vts[buf][sdst + 4096], vg + 64);                         \
    async16(&Vts[buf][sdst + 6144], vg + (size_t)32 * SEQ + 64);      \
  } while (0)

#pragma unroll 1
  for (int seg = 0; seg < 2; ++seg) {
    const int qi = seg ? pp : (31 - pp);   // big tile first
    const int qw = qi * 64 + wave * 16;    // wave's q base
    const int nt = (qi + 2) >> 1;          // 128-wide k-tiles

    bf16x8 qf0 = *(const bf16x8*)&Qh[(size_t)(qw + lrow) * DIMM + quad * 8];
    bf16x8 qf1 = *(const bf16x8*)&Qh[(size_t)(qw + lrow) * DIMM + 32 + quad * 8];

    const bf16* kg = Kh + (size_t)srow * DIMM + sx;
    const bf16* vg = Vth + (size_t)srow * SEQ + sx;

    // prologue: stage tile 0 into buf 0 (prior seg's reads done: its loop
    // ends with __syncthreads; epilogue touches only registers)
    ATT_STAGE(0, kg, vg);
    __syncthreads();

    f32x4 lacc = {};
    f32x4 o_acc[4] = {};
    int cur = 0;

    for (int kt = 0; kt < nt; ++kt) {
      if (kt + 1 < nt) {
        kg += 128 * DIMM; vg += 128;
        const int nb = cur ^ 1;
        ATT_STAGE(nb, kg, vg);
      }
      const bf16* Kc = Ks[cur];
      const bf16* Vc = Vts[cur];
      // ---- S^T = K Q^T from LDS (Q pre-scaled by C1 at qkv) ----
      f32x4 s[8];
#pragma unroll
      for (int gg = 0; gg < 8; ++gg) {
        s[gg] = f32x4{};
        bf16x8 kf0 = *(const bf16x8*)&Kc[(gg * 16 + lrow) * 64 + cx0];
        bf16x8 kf1 = *(const bf16x8*)&Kc[(gg * 16 + lrow) * 64 + cx1];
        s[gg] = __builtin_amdgcn_mfma_f32_16x16x32_bf16(kf0, qf0, s[gg], 0, 0, 0);
        s[gg] = __builtin_amdgcn_mfma_f32_16x16x32_bf16(kf1, qf1, s[gg], 0, 0, 0);
      }
      // ---- causal mask: only the last tile (covers diagonal + overshoot) --
      if (kt == nt - 1) {
        const int qrow = qw + lrow;
        const int kbase = kt * 128;
#pragma unroll
        for (int gg = 0; gg < 8; ++gg)
#pragma unroll
          for (int r = 0; r < 4; ++r)
            s[gg][r] = (kbase + gg * 16 + quad * 4 + r > qrow) ? -1e30f : s[gg][r];
      }
      // ---- max-free softmax: p = exp2(s); 4 independent sum chains ----
      bf16x8 pf0, pf1, pf2, pf3;         // PV B-fragments, built in-register
#pragma unroll
      for (int gg = 0; gg < 8; ++gg)
#pragma unroll
        for (int r = 0; r < 4; ++r) {
          const float p = __builtin_amdgcn_exp2f(s[gg][r]);
          lacc[r] += p;
          if      (gg < 2) pf0[(gg & 1) * 4 + r] = (bf16)p;
          else if (gg < 4) pf1[(gg & 1) * 4 + r] = (bf16)p;
          else if (gg < 6) pf2[(gg & 1) * 4 + r] = (bf16)p;
          else             pf3[(gg & 1) * 4 + r] = (bf16)p;
        }
      // ---- O^T += Vt P^T ; k-permuted Vt -> contiguous b128 reads --------
#pragma unroll
      for (int dt = 0; dt < 4; ++dt) {
        const bf16* Vr0 = &Vc[(dt * 16 + lrow) * 64];          // k sub 0
        const bf16* Vr1 = &Vc[4096 + (dt * 16 + lrow) * 64];   // k sub 1
        bf16x8 vA = *(const bf16x8*)&Vr0[cx0];
        bf16x8 vB = *(const bf16x8*)&Vr0[cx1];
        bf16x8 vC = *(const bf16x8*)&Vr1[cx0];
        bf16x8 vD = *(const bf16x8*)&Vr1[cx1];
        o_acc[dt] = __builtin_amdgcn_mfma_f32_16x16x32_bf16(vA, pf0, o_acc[dt], 0, 0, 0);
        o_acc[dt] = __builtin_amdgcn_mfma_f32_16x16x32_bf16(vB, pf1, o_acc[dt], 0, 0, 0);
        o_acc[dt] = __builtin_amdgcn_mfma_f32_16x16x32_bf16(vC, pf2, o_acc[dt], 0, 0, 0);
        o_acc[dt] = __builtin_amdgcn_mfma_f32_16x16x32_bf16(vD, pf3, o_acc[dt], 0, 0, 0);
      }
      __syncthreads();   // drains async staging; protects buffer swap
      cur ^= 1;
    }

    // ---- epilogue: cross-lane l reduce (registers only; no LDS) ----
    float lsum = (lacc[0] + lacc[1]) + (lacc[2] + lacc[3]);
    lsum += __shfl_xor(lsum, 16);
    lsum += __shfl_xor(lsum, 32);
    const float rl = __builtin_amdgcn_rcpf(lsum);
    bf16* Ob = O + (size_t)(b * SEQ + qw + lrow) * DIMM + h * HD;
#pragma unroll
    for (int dt = 0; dt < 4; ++dt) {
      bf16x4 ov;
#pragma unroll
      for (int r = 0; r < 4; ++r)
        ov[r] = (bf16)(o_acc[dt][r] * rl);
      *(bf16x4*)&Ob[dt * 16 + quad * 4] = ov;
    }
  }
#undef ATT_STAGE
}

// ---------------- launch ----------------
extern "C" void kernel_launch(void* const* d_in, const int* in_sizes, int n_in,
                              void* d_out, int out_size, void* d_ws, size_t ws_size,
                              hipStream_t stream) {
  const float* x  = (const float*)d_in[0];
  const float* wq = (const float*)d_in[1];
  const float* wk = (const float*)d_in[2];
  const float* wv = (const float*)d_in[3];
  const float* wo = (const float*)d_in[4];

  const size_t M4 = (size_t)MTOT * DIMM;  // 4M elems
  bf16* xb  = (bf16*)d_ws;                // 4M   (reused as CTX after qkv)
  bf16* Wb  = xb + M4;                    // 4M: [wq|wk|wv|wo]
  bf16* Q   = Wb + M4;                    // 4M
  bf16* Kb  = Q + M4;                     // 4M
  bf16* Vt  = Kb + M4;                    // 4M
  bf16* CTX = xb;                         // alias: xb dead after qkv_gemm
  float* out = (float*)d_out;

  convert_all<<<dim3(1024), dim3(256), 0, stream>>>(x, wq, wk, wv, wo, xb, Wb);
  qkv_gemm<<<dim3(512), dim3(256), 0, stream>>>(xb, Wb, Q, Kb, Vt);
  attn<<<dim3(512), dim3(256), 0, stream>>>(Q, Kb, Vt, CTX);
  proj_gemm<<<dim3(1024), dim3(256), 0, stream>>>(CTX, Wb + 3 * 1048576, out);
}

// Round 15
// 158.073 us; speedup vs baseline: 1.0051x; 1.0051x over previous
//
#include <hip/hip_runtime.h>
#include <stdint.h>

#define DIN 1024
#define DIMM 1024
#define NH 16
#define HD 64
#define SEQ 2048
#define BATCH 2
#define MTOT (BATCH*SEQ)   // 4096
#define SCALE 0.125f       // 1/sqrt(64)

typedef __bf16 bf16;
typedef __bf16 bf16x8 __attribute__((ext_vector_type(8)));
typedef __bf16 bf16x4 __attribute__((ext_vector_type(4)));
typedef float f32x4 __attribute__((ext_vector_type(4)));

// async global->LDS, 16B per lane (HW: wave-uniform LDS base + lane*16).
// Staged tiles use an XOR swizzle: LDS slot (row, c8) holds global col-group
// c8 ^ (row & 7); readers XOR their col-group by (row & 7). Spreads stride-64
// fragment reads across all 32 banks with zero padding.
__device__ __forceinline__ void async16(bf16* lds, const bf16* g) {
  __builtin_amdgcn_global_load_lds(
      (const __attribute__((address_space(1))) void*)g,
      (__attribute__((address_space(3))) void*)lds, 16, 0, 0);
}

#define WAIT_VM(n)  asm volatile("s_waitcnt vmcnt(" #n ")" ::: "memory")
#define BARRIER()   asm volatile("s_barrier" ::: "memory")

// ---------------- fp32 -> bf16 convert: x (4M) + wq|wk|wv|wo (4M) ----------
__global__ __launch_bounds__(256) void convert_all(const float* __restrict__ x,
                                                   const float* __restrict__ wq,
                                                   const float* __restrict__ wk,
                                                   const float* __restrict__ wv,
                                                   const float* __restrict__ wo,
                                                   bf16* __restrict__ xb,
                                                   bf16* __restrict__ Wb) {
  const int t = blockIdx.x * 256 + threadIdx.x;
#pragma unroll
  for (int i = 0; i < 4; ++i) {
    const int c = t + i * 262144;   // 8-elem chunk id, total 1048576
    const float* src;
    bf16* dst;
    if (c < 524288) {               // x: 4M elems
      src = x + (size_t)c * 8;
      dst = xb + (size_t)c * 8;
    } else {
      const int cw = c - 524288;
      const int w = cw >> 17;       // 131072 chunks per weight
      const int off = (cw & 131071) * 8;
      const float* wp = (w == 0) ? wq : (w == 1) ? wk : (w == 2) ? wv : wo;
      src = wp + off;
      dst = Wb + (size_t)w * 1048576 + off;
    }
    f32x4 a = *(const f32x4*)src;
    f32x4 b = *(const f32x4*)(src + 4);
    bf16x8 r;
    r[0] = (bf16)a[0]; r[1] = (bf16)a[1]; r[2] = (bf16)a[2]; r[3] = (bf16)a[3];
    r[4] = (bf16)b[0]; r[5] = (bf16)b[1]; r[6] = (bf16)b[2]; r[7] = (bf16)b[3];
    *(bf16x8*)dst = r;
  }
}

// ---------------- QKV GEMM v5: 128x192 tile, 2 blocks/CU, counted vmcnt ---
// Q region written PRE-SCALED by C1 = SCALE*log2(e) so attn softmax is
// p = exp2(s) directly. Vt is written with a k-PERMUTATION within each
// 32-col group (k' = quad*8 + b*4 + r): PV's B-fragment (P, packed at
// j=b*4+r from original k=16b+4quad+r) then matches a CONTIGUOUS 16B
// A-fragment read of V -> attn's V reads become conflict-free b128 at the
// same swizzled col-groups as K (the contraction is permutation-invariant
// when both operands agree).
__global__ __launch_bounds__(256, 2) void qkv_gemm(const bf16* __restrict__ A,
                                                   const bf16* __restrict__ B,
                                                   bf16* __restrict__ Q,
                                                   bf16* __restrict__ Kb,
                                                   bf16* __restrict__ Vt) {
  __shared__ bf16 As0[128 * 64];   // 16 KB
  __shared__ bf16 As1[128 * 64];
  __shared__ bf16 Bs0[192 * 64];   // 24 KB
  __shared__ bf16 Bs1[192 * 64];
  const int tid  = threadIdx.x;
  const int lane = tid & 63;
  const int wave = tid >> 6;
  const int lrow = lane & 15;
  const int quad = lane >> 4;
  const int wrow = wave >> 1;            // 0..1 -> 64-row band
  const int wcol = wave & 1;             // 0..1 -> 96-col band
  const int lin  = blockIdx.x;           // 0..511
  const int xcd  = lin & 7;
  const int idx  = lin >> 3;             // 0..63
  const int nbase = (xcd * 2 + (idx & 1)) * 192;  // 16 N-tiles, 2 per XCD
  const int mbase = (idx >> 1) * 128;             // 32 M-tiles

  // staging: 256 thr cover 32 rows x 128 B per pass; lane->lane*16B in LDS
  const int srow = tid >> 3;             // 0..31
  const int sdst = srow * 64 + (tid & 7) * 8;      // LDS dest (elems)
  const int sx   = ((tid & 7) ^ (srow & 7)) * 8;   // swizzled global col

  const bf16* ap = A + (size_t)(mbase + srow) * DIN + sx;
  const bf16* bp = B + (size_t)(nbase + srow) * DIN + sx;

  f32x4 acc[4][6] = {};

#define QKV_STAGE(Asb, Bsb)                                          \
  do {                                                               \
    _Pragma("unroll")                                                \
    for (int i = 0; i < 4; ++i)                                      \
      async16(&Asb[sdst + i * 2048], ap + (size_t)i * 32 * DIN);     \
    _Pragma("unroll")                                                \
    for (int i = 0; i < 6; ++i)                                      \
      async16(&Bsb[sdst + i * 2048], bp + (size_t)i * 32 * DIN);     \
  } while (0)

#define QKV_COMPUTE(Asb, Bsb)                                        \
  do {                                                               \
    __builtin_amdgcn_s_setprio(1);                                   \
    _Pragma("unroll")                                                \
    for (int h = 0; h < 2; ++h) {                                    \
      const int cx = ((h * 4 + quad) ^ (lrow & 7)) * 8;              \
      bf16x8 af[4], bfr[6];                                          \
      _Pragma("unroll")                                              \
      for (int i = 0; i < 4; ++i)                                    \
        af[i] = *(const bf16x8*)&Asb[(wrow * 64 + i * 16 + lrow) * 64 + cx]; \
      _Pragma("unroll")                                              \
      for (int j = 0; j < 6; ++j)                                    \
        bfr[j] = *(const bf16x8*)&Bsb[(wcol * 96 + j * 16 + lrow) * 64 + cx]; \
      _Pragma("unroll")                                              \
      for (int i = 0; i < 4; ++i)                                    \
        _Pragma("unroll")                                            \
        for (int j = 0; j < 6; ++j)                                  \
          acc[i][j] = __builtin_amdgcn_mfma_f32_16x16x32_bf16(af[i], bfr[j], acc[i][j], 0, 0, 0); \
    }                                                                \
    __builtin_amdgcn_s_setprio(0);                                   \
  } while (0)

  // prologue: stage K-step 0 into buf0; full drain (only these 10 in flight)
  QKV_STAGE(As0, Bs0);
  WAIT_VM(0);
  BARRIER();

  // 16 K-steps, unrolled x2 for compile-time buffer selection.
#pragma unroll 1
  for (int t = 0; t < 16; t += 2) {
    // ---- even step: compute buf0, stage t+1 into buf1 ----
    ap += 64; bp += 64;
    QKV_STAGE(As1, Bs1);
    WAIT_VM(10);         // own buf0 loads done; buf1's 10 stay in flight
    BARRIER();           // all waves: buf0 fully landed
    QKV_COMPUTE(As0, Bs0);
    BARRIER();           // all reads of buf0 done before its next overwrite
    // ---- odd step: compute buf1, stage t+2 into buf0 ----
    if (t + 2 < 16) {
      ap += 64; bp += 64;
      QKV_STAGE(As0, Bs0);
      WAIT_VM(10);       // own buf1 loads done
    } else {
      WAIT_VM(0);
    }
    BARRIER();
    QKV_COMPUTE(As1, Bs1);
    BARRIER();
  }

#undef QKV_STAGE
#undef QKV_COMPUTE

  // ---- epilogue: region-split C write (Q pre-scaled; Vt k-permuted) ----
  const float C1 = 0.18033688f;          // SCALE * log2(e)
#pragma unroll
  for (int mt = 0; mt < 4; ++mt) {
    const int m0 = mbase + wrow * 64 + mt * 16 + quad * 4;
#pragma unroll
    for (int nt = 0; nt < 6; ++nt) {
      const int n16 = nbase + wcol * 96 + nt * 16;  // 16-aligned; frag-uniform
      const int n = n16 + lrow;
      if (n16 < 1024) {
#pragma unroll
        for (int rr = 0; rr < 4; ++rr)
          Q[(size_t)(m0 + rr) * 1024 + n] = (bf16)(acc[mt][nt][rr] * C1);
      } else if (n16 < 2048) {
#pragma unroll
        for (int rr = 0; rr < 4; ++rr)
          Kb[(size_t)(m0 + rr) * 1024 + (n - 1024)] = (bf16)acc[mt][nt][rr];
      } else {
        const int nn = n - 2048;
        const int row = ((m0 >> 11) * 16 + (nn >> 6)) * 64 + (nn & 63);
        const int kb  = m0 & 2047;       // original k (seq within batch)
        const int colp = (kb & ~31) | (quad * 8) | ((mt & 1) * 4);  // k-perm
        bf16x4 ov;
#pragma unroll
        for (int rr = 0; rr < 4; ++rr) ov[rr] = (bf16)acc[mt][nt][rr];
        *(bf16x4*)&Vt[(size_t)row * SEQ + colp] = ov;
      }
    }
  }
}

// ---------------- proj GEMM v2: 128x64, 2 blocks/CU, counted vmcnt --------
__global__ __launch_bounds__(256, 2) void proj_gemm(const bf16* __restrict__ A,
                                                    const bf16* __restrict__ B,
                                                    float* __restrict__ C) {
  __shared__ bf16 As0[128 * 64];   // 16 KB
  __shared__ bf16 As1[128 * 64];
  __shared__ bf16 Bs0[64 * 64];    // 8 KB
  __shared__ bf16 Bs1[64 * 64];
  const int tid  = threadIdx.x;
  const int lane = tid & 63;
  const int wave = tid >> 6;
  const int lrow = lane & 15;
  const int quad = lane >> 4;
  const int wr = (wave >> 1) * 64;
  const int wc = (wave & 1) * 32;
  const int lin = blockIdx.x;            // 0..511
  const int xcd = lin & 7;
  const int idx = lin >> 3;              // 0..63
  const int nbase = (xcd * 2 + (idx & 1)) * 64;  // 16 N-tiles, 2 per XCD
  const int mbase = (idx >> 1) * 128;            // 32 M-tiles
  const int srow = tid >> 3;
  const int sdst = srow * 64 + (tid & 7) * 8;
  const int sx   = ((tid & 7) ^ (srow & 7)) * 8;

  const bf16* ap = A + (size_t)(mbase + srow) * DIMM + sx;
  const bf16* bp = B + (size_t)(nbase + srow) * DIMM + sx;

  f32x4 acc[4][2] = {};

#define PRJ_STAGE(Asb, Bsb)                                          \
  do {                                                               \
    _Pragma("unroll")                                                \
    for (int i = 0; i < 4; ++i)                                      \
      async16(&Asb[sdst + i * 2048], ap + (size_t)i * 32 * DIMM);    \
    _Pragma("unroll")                                                \
    for (int i = 0; i < 2; ++i)                                      \
      async16(&Bsb[sdst + i * 2048], bp + (size_t)i * 32 * DIMM);    \
  } while (0)

#define PRJ_COMPUTE(Asb, Bsb)                                        \
  do {                                                               \
    __builtin_amdgcn_s_setprio(1);                                   \
    _Pragma("unroll")                                                \
    for (int h = 0; h < 2; ++h) {                                    \
      const int cx = ((h * 4 + quad) ^ (lrow & 7)) * 8;              \
      bf16x8 af[4], bfr[2];                                          \
      _Pragma("unroll")                                              \
      for (int i = 0; i < 4; ++i)                                    \
        af[i] = *(const bf16x8*)&Asb[(wr + i * 16 + lrow) * 64 + cx]; \
      _Pragma("unroll")                                              \
      for (int i = 0; i < 2; ++i)                                    \
        bfr[i] = *(const bf16x8*)&Bsb[(wc + i * 16 + lrow) * 64 + cx]; \
      _Pragma("unroll")                                              \
      for (int mt = 0; mt < 4; ++mt)                                 \
        _Pragma("unroll")                                            \
        for (int nt = 0; nt < 2; ++nt)                               \
          acc[mt][nt] = __builtin_amdgcn_mfma_f32_16x16x32_bf16(af[mt], bfr[nt], acc[mt][nt], 0, 0, 0); \
    }                                                                \
    __builtin_amdgcn_s_setprio(0);                                   \
  } while (0)

  PRJ_STAGE(As0, Bs0);
  WAIT_VM(0);
  BARRIER();

#pragma unroll 1
  for (int t = 0; t < 16; t += 2) {
    ap += 64; bp += 64;
    PRJ_STAGE(As1, Bs1);
    WAIT_VM(6);
    BARRIER();
    PRJ_COMPUTE(As0, Bs0);
    BARRIER();
    if (t + 2 < 16) {
      ap += 64; bp += 64;
      PRJ_STAGE(As0, Bs0);
      WAIT_VM(6);
    } else {
      WAIT_VM(0);
    }
    BARRIER();
    PRJ_COMPUTE(As1, Bs1);
    BARRIER();
  }

#undef PRJ_STAGE
#undef PRJ_COMPUTE

#pragma unroll
  for (int mt = 0; mt < 4; ++mt) {
    const int m0 = mbase + wr + mt * 16 + quad * 4;
#pragma unroll
    for (int nt = 0; nt < 2; ++nt) {
      const int n = nbase + wc + nt * 16 + lrow;
#pragma unroll
      for (int rr = 0; rr < 4; ++rr)
        C[(size_t)(m0 + rr) * 1024 + n] = acc[mt][nt][rr];
    }
  }
}

// ---------------- Causal flash attention v6: KVBLK=128 + b128 V reads -----
// Vt's k-dim is pre-permuted at the qkv write so the PV A-fragment is a
// contiguous 16B read at the SAME swizzled col-groups as K (cx0/cx1):
// conflict-free ds_read_b128, replacing 8 4-way-conflicting b64 gathers.
// Pair (31-p, p) at 128-wide = exactly 17 iterations for every p. 512
// blocks, 2/CU, LDS 64 KB.
__global__ __launch_bounds__(256, 2) void attn(const bf16* __restrict__ Q,
                                               const bf16* __restrict__ K,
                                               const bf16* __restrict__ Vt,
                                               bf16* __restrict__ O) {
  __shared__ bf16 Ks[2][128 * 64];   // 16 KB each buf
  __shared__ bf16 Vts[2][128 * 64];  // 2 sub-tiles of [64][64] per buf
  const int tid  = threadIdx.x;
  const int wave = tid >> 6;
  const int lane = tid & 63;
  const int lrow = lane & 15;
  const int quad = lane >> 4;
  const int lin  = blockIdx.x;           // 0..511
  const int bh   = lin & 31;             // same bh -> same XCD residue (L2)
  const int pp   = lin >> 5;             // 0..15: pair id
  const int b = bh >> 4;
  const int h = bh & 15;

  const bf16* Qh  = Q  + (size_t)(b * SEQ) * DIMM + h * HD;
  const bf16* Kh  = K  + (size_t)(b * SEQ) * DIMM + h * HD;
  const bf16* Vth = Vt + (size_t)bh * 64 * SEQ;

  // staging coords: 256 thr cover 32 rows x 128B per pass; swizzled src col
  const int srow = tid >> 3;             // 0..31
  const int sdst = srow * 64 + (tid & 7) * 8;      // LDS dest (elems)
  const int sx   = ((tid & 7) ^ (srow & 7)) * 8;   // (srow+32)&7 == srow&7
  const int cx0 = ((0 + quad) ^ (lrow & 7)) * 8;
  const int cx1 = ((4 + quad) ^ (lrow & 7)) * 8;

  // stage one 128-row K tile + one 64x128 V tile (8 passes total)
#define ATT_STAGE(buf, kg, vg)                                        \
  do {                                                                \
    _Pragma("unroll")                                                 \
    for (int i = 0; i < 4; ++i)                                       \
      async16(&Ks[buf][sdst + i * 2048], kg + (size_t)i * 32 * DIMM); \
    async16(&Vts[buf][sdst],        vg);                              \
    async16(&Vts[buf][sdst + 2048], vg + (size_t)32 * SEQ);           \
    async16(&Vts[buf][sdst + 4096], vg + 64);                         \
    async16(&Vts[buf][sdst + 6144], vg + (size_t)32 * SEQ + 64);      \
  } while (0)

#pragma unroll 1
  for (int seg = 0; seg < 2; ++seg) {
    const int qi = seg ? pp : (31 - pp);   // big tile first
    const int qw = qi * 64 + wave * 16;    // wave's q base
    const int nt = (qi + 2) >> 1;          // 128-wide k-tiles

    bf16x8 qf0 = *(const bf16x8*)&Qh[(size_t)(qw + lrow) * DIMM + quad * 8];
    bf16x8 qf1 = *(const bf16x8*)&Qh[(size_t)(qw + lrow) * DIMM + 32 + quad * 8];

    const bf16* kg = Kh + (size_t)srow * DIMM + sx;
    const bf16* vg = Vth + (size_t)srow * SEQ + sx;

    // prologue: stage tile 0 into buf 0 (prior seg's reads done: its loop
    // ends with __syncthreads; epilogue touches only registers)
    ATT_STAGE(0, kg, vg);
    __syncthreads();

    f32x4 lacc = {};
    f32x4 o_acc[4] = {};
    int cur = 0;

    for (int kt = 0; kt < nt; ++kt) {
      if (kt + 1 < nt) {
        kg += 128 * DIMM; vg += 128;
        const int nb = cur ^ 1;
        ATT_STAGE(nb, kg, vg);
      }
      const bf16* Kc = Ks[cur];
      const bf16* Vc = Vts[cur];
      // ---- S^T = K Q^T from LDS (Q pre-scaled by C1 at qkv) ----
      f32x4 s[8];
#pragma unroll
      for (int gg = 0; gg < 8; ++gg) {
        s[gg] = f32x4{};
        bf16x8 kf0 = *(const bf16x8*)&Kc[(gg * 16 + lrow) * 64 + cx0];
        bf16x8 kf1 = *(const bf16x8*)&Kc[(gg * 16 + lrow) * 64 + cx1];
        s[gg] = __builtin_amdgcn_mfma_f32_16x16x32_bf16(kf0, qf0, s[gg], 0, 0, 0);
        s[gg] = __builtin_amdgcn_mfma_f32_16x16x32_bf16(kf1, qf1, s[gg], 0, 0, 0);
      }
      // ---- causal mask: only the last tile (covers diagonal + overshoot) --
      if (kt == nt - 1) {
        const int qrow = qw + lrow;
        const int kbase = kt * 128;
#pragma unroll
        for (int gg = 0; gg < 8; ++gg)
#pragma unroll
          for (int r = 0; r < 4; ++r)
            s[gg][r] = (kbase + gg * 16 + quad * 4 + r > qrow) ? -1e30f : s[gg][r];
      }
      // ---- max-free softmax: p = exp2(s); 4 independent sum chains ----
      bf16x8 pf0, pf1, pf2, pf3;         // PV B-fragments, built in-register
#pragma unroll
      for (int gg = 0; gg < 8; ++gg)
#pragma unroll
        for (int r = 0; r < 4; ++r) {
          const float p = __builtin_amdgcn_exp2f(s[gg][r]);
          lacc[r] += p;
          if      (gg < 2) pf0[(gg & 1) * 4 + r] = (bf16)p;
          else if (gg < 4) pf1[(gg & 1) * 4 + r] = (bf16)p;
          else if (gg < 6) pf2[(gg & 1) * 4 + r] = (bf16)p;
          else             pf3[(gg & 1) * 4 + r] = (bf16)p;
        }
      // ---- O^T += Vt P^T ; k-permuted Vt -> contiguous b128 reads --------
#pragma unroll
      for (int dt = 0; dt < 4; ++dt) {
        const bf16* Vr0 = &Vc[(dt * 16 + lrow) * 64];          // k sub 0
        const bf16* Vr1 = &Vc[4096 + (dt * 16 + lrow) * 64];   // k sub 1
        bf16x8 vA = *(const bf16x8*)&Vr0[cx0];
        bf16x8 vB = *(const bf16x8*)&Vr0[cx1];
        bf16x8 vC = *(const bf16x8*)&Vr1[cx0];
        bf16x8 vD = *(const bf16x8*)&Vr1[cx1];
        o_acc[dt] = __builtin_amdgcn_mfma_f32_16x16x32_bf16(vA, pf0, o_acc[dt], 0, 0, 0);
        o_acc[dt] = __builtin_amdgcn_mfma_f32_16x16x32_bf16(vB, pf1, o_acc[dt], 0, 0, 0);
        o_acc[dt] = __builtin_amdgcn_mfma_f32_16x16x32_bf16(vC, pf2, o_acc[dt], 0, 0, 0);
        o_acc[dt] = __builtin_amdgcn_mfma_f32_16x16x32_bf16(vD, pf3, o_acc[dt], 0, 0, 0);
      }
      __syncthreads();   // drains async staging; protects buffer swap
      cur ^= 1;
    }

    // ---- epilogue: cross-lane l reduce (registers only; no LDS) ----
    float lsum = (lacc[0] + lacc[1]) + (lacc[2] + lacc[3]);
    lsum += __shfl_xor(lsum, 16);
    lsum += __shfl_xor(lsum, 32);
    const float rl = __builtin_amdgcn_rcpf(lsum);
    bf16* Ob = O + (size_t)(b * SEQ + qw + lrow) * DIMM + h * HD;
#pragma unroll
    for (int dt = 0; dt < 4; ++dt) {
      bf16x4 ov;
#pragma unroll
      for (int r = 0; r < 4; ++r)
        ov[r] = (bf16)(o_acc[dt][r] * rl);
      *(bf16x4*)&Ob[dt * 16 + quad * 4] = ov;
    }
  }
#undef ATT_STAGE
}

// ---------------- launch ----------------
extern "C" void kernel_launch(void* const* d_in, const int* in_sizes, int n_in,
                              void* d_out, int out_size, void* d_ws, size_t ws_size,
                              hipStream_t stream) {
  const float* x  = (const float*)d_in[0];
  const float* wq = (const float*)d_in[1];
  const float* wk = (const float*)d_in[2];
  const float* wv = (const float*)d_in[3];
  const float* wo = (const float*)d_in[4];

  const size_t M4 = (size_t)MTOT * DIMM;  // 4M elems
  bf16* xb  = (bf16*)d_ws;                // 4M   (reused as CTX after qkv)
  bf16* Wb  = xb + M4;                    // 4M: [wq|wk|wv|wo]
  bf16* Q   = Wb + M4;                    // 4M
  bf16* Kb  = Q + M4;                     // 4M
  bf16* Vt  = Kb + M4;                    // 4M
  bf16* CTX = xb;                         // alias: xb dead after qkv_gemm
  float* out = (float*)d_out;

  convert_all<<<dim3(1024), dim3(256), 0, stream>>>(x, wq, wk, wv, wo, xb, Wb);
  qkv_gemm<<<dim3(512), dim3(256), 0, stream>>>(xb, Wb, Q, Kb, Vt);
  attn<<<dim3(512), dim3(256), 0, stream>>>(Q, Kb, Vt, CTX);
  proj_gemm<<<dim3(512), dim3(256), 0, stream>>>(CTX, Wb + 3 * 1048576, out);
}

// Round 16
// 157.107 us; speedup vs baseline: 1.0113x; 1.0061x over previous
//
#include <hip/hip_runtime.h>
#include <stdint.h>

#define DIN 1024
#define DIMM 1024
#define NH 16
#define HD 64
#define SEQ 2048
#define BATCH 2
#define MTOT (BATCH*SEQ)   // 4096
#define SCALE 0.125f       // 1/sqrt(64)

typedef __bf16 bf16;
typedef __bf16 bf16x8 __attribute__((ext_vector_type(8)));
typedef __bf16 bf16x4 __attribute__((ext_vector_type(4)));
typedef float f32x4 __attribute__((ext_vector_type(4)));

// async global->LDS, 16B per lane (HW: wave-uniform LDS base + lane*16).
// Staged tiles use an XOR swizzle: LDS slot (row, c8) holds global col-group
// c8 ^ (row & 7); readers XOR their col-group by (row & 7). Spreads stride-64
// fragment reads across all 32 banks with zero padding.
__device__ __forceinline__ void async16(bf16* lds, const bf16* g) {
  __builtin_amdgcn_global_load_lds(
      (const __attribute__((address_space(1))) void*)g,
      (__attribute__((address_space(3))) void*)lds, 16, 0, 0);
}

#define WAIT_VM(n)  asm volatile("s_waitcnt vmcnt(" #n ")" ::: "memory")
#define BARRIER()   asm volatile("s_barrier" ::: "memory")

// ---------------- fp32 -> bf16 convert: x (4M) + wq|wk|wv|wo (4M) ----------
__global__ __launch_bounds__(256) void convert_all(const float* __restrict__ x,
                                                   const float* __restrict__ wq,
                                                   const float* __restrict__ wk,
                                                   const float* __restrict__ wv,
                                                   const float* __restrict__ wo,
                                                   bf16* __restrict__ xb,
                                                   bf16* __restrict__ Wb) {
  const int t = blockIdx.x * 256 + threadIdx.x;
#pragma unroll
  for (int i = 0; i < 4; ++i) {
    const int c = t + i * 262144;   // 8-elem chunk id, total 1048576
    const float* src;
    bf16* dst;
    if (c < 524288) {               // x: 4M elems
      src = x + (size_t)c * 8;
      dst = xb + (size_t)c * 8;
    } else {
      const int cw = c - 524288;
      const int w = cw >> 17;       // 131072 chunks per weight
      const int off = (cw & 131071) * 8;
      const float* wp = (w == 0) ? wq : (w == 1) ? wk : (w == 2) ? wv : wo;
      src = wp + off;
      dst = Wb + (size_t)w * 1048576 + off;
    }
    f32x4 a = *(const f32x4*)src;
    f32x4 b = *(const f32x4*)(src + 4);
    bf16x8 r;
    r[0] = (bf16)a[0]; r[1] = (bf16)a[1]; r[2] = (bf16)a[2]; r[3] = (bf16)a[3];
    r[4] = (bf16)b[0]; r[5] = (bf16)b[1]; r[6] = (bf16)b[2]; r[7] = (bf16)b[3];
    *(bf16x8*)dst = r;
  }
}

// ---------------- QKV GEMM v5: 128x192 tile, 2 blocks/CU, counted vmcnt ---
// Q region written PRE-SCALED by C1 = SCALE*log2(e) so attn softmax is
// p = exp2(s) directly. Vt is written with a k-PERMUTATION within each
// 32-col group (k' = quad*8 + b*4 + r): PV's B-fragment (P, packed at
// j=b*4+r from original k=16b+4quad+r) then matches a CONTIGUOUS 16B
// A-fragment read of V -> attn's V reads become conflict-free b128 at the
// same swizzled col-groups as K.
__global__ __launch_bounds__(256, 2) void qkv_gemm(const bf16* __restrict__ A,
                                                   const bf16* __restrict__ B,
                                                   bf16* __restrict__ Q,
                                                   bf16* __restrict__ Kb,
                                                   bf16* __restrict__ Vt) {
  __shared__ bf16 As0[128 * 64];   // 16 KB
  __shared__ bf16 As1[128 * 64];
  __shared__ bf16 Bs0[192 * 64];   // 24 KB
  __shared__ bf16 Bs1[192 * 64];
  const int tid  = threadIdx.x;
  const int lane = tid & 63;
  const int wave = tid >> 6;
  const int lrow = lane & 15;
  const int quad = lane >> 4;
  const int wrow = wave >> 1;            // 0..1 -> 64-row band
  const int wcol = wave & 1;             // 0..1 -> 96-col band
  const int lin  = blockIdx.x;           // 0..511
  const int xcd  = lin & 7;
  const int idx  = lin >> 3;             // 0..63
  const int nbase = (xcd * 2 + (idx & 1)) * 192;  // 16 N-tiles, 2 per XCD
  const int mbase = (idx >> 1) * 128;             // 32 M-tiles

  // staging: 256 thr cover 32 rows x 128 B per pass; lane->lane*16B in LDS
  const int srow = tid >> 3;             // 0..31
  const int sdst = srow * 64 + (tid & 7) * 8;      // LDS dest (elems)
  const int sx   = ((tid & 7) ^ (srow & 7)) * 8;   // swizzled global col

  const bf16* ap = A + (size_t)(mbase + srow) * DIN + sx;
  const bf16* bp = B + (size_t)(nbase + srow) * DIN + sx;

  f32x4 acc[4][6] = {};

#define QKV_STAGE(Asb, Bsb)                                          \
  do {                                                               \
    _Pragma("unroll")                                                \
    for (int i = 0; i < 4; ++i)                                      \
      async16(&Asb[sdst + i * 2048], ap + (size_t)i * 32 * DIN);     \
    _Pragma("unroll")                                                \
    for (int i = 0; i < 6; ++i)                                      \
      async16(&Bsb[sdst + i * 2048], bp + (size_t)i * 32 * DIN);     \
  } while (0)

#define QKV_COMPUTE(Asb, Bsb)                                        \
  do {                                                               \
    __builtin_amdgcn_s_setprio(1);                                   \
    _Pragma("unroll")                                                \
    for (int h = 0; h < 2; ++h) {                                    \
      const int cx = ((h * 4 + quad) ^ (lrow & 7)) * 8;              \
      bf16x8 af[4], bfr[6];                                          \
      _Pragma("unroll")                                              \
      for (int i = 0; i < 4; ++i)                                    \
        af[i] = *(const bf16x8*)&Asb[(wrow * 64 + i * 16 + lrow) * 64 + cx]; \
      _Pragma("unroll")                                              \
      for (int j = 0; j < 6; ++j)                                    \
        bfr[j] = *(const bf16x8*)&Bsb[(wcol * 96 + j * 16 + lrow) * 64 + cx]; \
      _Pragma("unroll")                                              \
      for (int i = 0; i < 4; ++i)                                    \
        _Pragma("unroll")                                            \
        for (int j = 0; j < 6; ++j)                                  \
          acc[i][j] = __builtin_amdgcn_mfma_f32_16x16x32_bf16(af[i], bfr[j], acc[i][j], 0, 0, 0); \
    }                                                                \
    __builtin_amdgcn_s_setprio(0);                                   \
  } while (0)

  // prologue: stage K-step 0 into buf0; full drain (only these 10 in flight)
  QKV_STAGE(As0, Bs0);
  WAIT_VM(0);
  BARRIER();

  // 16 K-steps, unrolled x2 for compile-time buffer selection.
#pragma unroll 1
  for (int t = 0; t < 16; t += 2) {
    // ---- even step: compute buf0, stage t+1 into buf1 ----
    ap += 64; bp += 64;
    QKV_STAGE(As1, Bs1);
    WAIT_VM(10);         // own buf0 loads done; buf1's 10 stay in flight
    BARRIER();           // all waves: buf0 fully landed
    QKV_COMPUTE(As0, Bs0);
    BARRIER();           // all reads of buf0 done before its next overwrite
    // ---- odd step: compute buf1, stage t+2 into buf0 ----
    if (t + 2 < 16) {
      ap += 64; bp += 64;
      QKV_STAGE(As0, Bs0);
      WAIT_VM(10);       // own buf1 loads done
    } else {
      WAIT_VM(0);
    }
    BARRIER();
    QKV_COMPUTE(As1, Bs1);
    BARRIER();
  }

#undef QKV_STAGE
#undef QKV_COMPUTE

  // ---- epilogue: region-split C write (Q pre-scaled; Vt k-permuted) ----
  const float C1 = 0.18033688f;          // SCALE * log2(e)
#pragma unroll
  for (int mt = 0; mt < 4; ++mt) {
    const int m0 = mbase + wrow * 64 + mt * 16 + quad * 4;
#pragma unroll
    for (int nt = 0; nt < 6; ++nt) {
      const int n16 = nbase + wcol * 96 + nt * 16;  // 16-aligned; frag-uniform
      const int n = n16 + lrow;
      if (n16 < 1024) {
#pragma unroll
        for (int rr = 0; rr < 4; ++rr)
          Q[(size_t)(m0 + rr) * 1024 + n] = (bf16)(acc[mt][nt][rr] * C1);
      } else if (n16 < 2048) {
#pragma unroll
        for (int rr = 0; rr < 4; ++rr)
          Kb[(size_t)(m0 + rr) * 1024 + (n - 1024)] = (bf16)acc[mt][nt][rr];
      } else {
        const int nn = n - 2048;
        const int row = ((m0 >> 11) * 16 + (nn >> 6)) * 64 + (nn & 63);
        const int kb  = m0 & 2047;       // original k (seq within batch)
        const int colp = (kb & ~31) | (quad * 8) | ((mt & 1) * 4);  // k-perm
        bf16x4 ov;
#pragma unroll
        for (int rr = 0; rr < 4; ++rr) ov[rr] = (bf16)acc[mt][nt][rr];
        *(bf16x4*)&Vt[(size_t)row * SEQ + colp] = ov;
      }
    }
  }
}

// ---------------- proj GEMM v2: 128x64, 2 blocks/CU, counted vmcnt --------
__global__ __launch_bounds__(256, 2) void proj_gemm(const bf16* __restrict__ A,
                                                    const bf16* __restrict__ B,
                                                    float* __restrict__ C) {
  __shared__ bf16 As0[128 * 64];   // 16 KB
  __shared__ bf16 As1[128 * 64];
  __shared__ bf16 Bs0[64 * 64];    // 8 KB
  __shared__ bf16 Bs1[64 * 64];
  const int tid  = threadIdx.x;
  const int lane = tid & 63;
  const int wave = tid >> 6;
  const int lrow = lane & 15;
  const int quad = lane >> 4;
  const int wr = (wave >> 1) * 64;
  const int wc = (wave & 1) * 32;
  const int lin = blockIdx.x;            // 0..511
  const int xcd = lin & 7;
  const int idx = lin >> 3;              // 0..63
  const int nbase = (xcd * 2 + (idx & 1)) * 64;  // 16 N-tiles, 2 per XCD
  const int mbase = (idx >> 1) * 128;            // 32 M-tiles
  const int srow = tid >> 3;
  const int sdst = srow * 64 + (tid & 7) * 8;
  const int sx   = ((tid & 7) ^ (srow & 7)) * 8;

  const bf16* ap = A + (size_t)(mbase + srow) * DIMM + sx;
  const bf16* bp = B + (size_t)(nbase + srow) * DIMM + sx;

  f32x4 acc[4][2] = {};

#define PRJ_STAGE(Asb, Bsb)                                          \
  do {                                                               \
    _Pragma("unroll")                                                \
    for (int i = 0; i < 4; ++i)                                      \
      async16(&Asb[sdst + i * 2048], ap + (size_t)i * 32 * DIMM);    \
    _Pragma("unroll")                                                \
    for (int i = 0; i < 2; ++i)                                      \
      async16(&Bsb[sdst + i * 2048], bp + (size_t)i * 32 * DIMM);    \
  } while (0)

#define PRJ_COMPUTE(Asb, Bsb)                                        \
  do {                                                               \
    __builtin_amdgcn_s_setprio(1);                                   \
    _Pragma("unroll")                                                \
    for (int h = 0; h < 2; ++h) {                                    \
      const int cx = ((h * 4 + quad) ^ (lrow & 7)) * 8;              \
      bf16x8 af[4], bfr[2];                                          \
      _Pragma("unroll")                                              \
      for (int i = 0; i < 4; ++i)                                    \
        af[i] = *(const bf16x8*)&Asb[(wr + i * 16 + lrow) * 64 + cx]; \
      _Pragma("unroll")                                              \
      for (int i = 0; i < 2; ++i)                                    \
        bfr[i] = *(const bf16x8*)&Bsb[(wc + i * 16 + lrow) * 64 + cx]; \
      _Pragma("unroll")                                              \
      for (int mt = 0; mt < 4; ++mt)                                 \
        _Pragma("unroll")                                            \
        for (int nt = 0; nt < 2; ++nt)                               \
          acc[mt][nt] = __builtin_amdgcn_mfma_f32_16x16x32_bf16(af[mt], bfr[nt], acc[mt][nt], 0, 0, 0); \
    }                                                                \
    __builtin_amdgcn_s_setprio(0);                                   \
  } while (0)

  PRJ_STAGE(As0, Bs0);
  WAIT_VM(0);
  BARRIER();

#pragma unroll 1
  for (int t = 0; t < 16; t += 2) {
    ap += 64; bp += 64;
    PRJ_STAGE(As1, Bs1);
    WAIT_VM(6);
    BARRIER();
    PRJ_COMPUTE(As0, Bs0);
    BARRIER();
    if (t + 2 < 16) {
      ap += 64; bp += 64;
      PRJ_STAGE(As0, Bs0);
      WAIT_VM(6);
    } else {
      WAIT_VM(0);
    }
    BARRIER();
    PRJ_COMPUTE(As1, Bs1);
    BARRIER();
  }

#undef PRJ_STAGE
#undef PRJ_COMPUTE

#pragma unroll
  for (int mt = 0; mt < 4; ++mt) {
    const int m0 = mbase + wr + mt * 16 + quad * 4;
#pragma unroll
    for (int nt = 0; nt < 2; ++nt) {
      const int n = nbase + wc + nt * 16 + lrow;
#pragma unroll
      for (int rr = 0; rr < 4; ++rr)
        C[(size_t)(m0 + rr) * 1024 + n] = acc[mt][nt][rr];
    }
  }
}

// ---------------- Causal flash attention v9: single-buf, 5 blocks/CU ------
// Combine the two proven levers (KVBLK=128 iteration count + many blocks/CU
// backfill, never before combined because dbuf KVBLK=128 = 64 KB caps at
// 2/CU). Single-buffered 32 KB LDS -> 5 blocks/CU. 1024 blocks, one 64-row
// q-tile each (nt = 1..16 iters, imbalanced; big-q blocks launch FIRST and
// retiring short blocks are backfilled — the R5 mechanism at 2.5x depth).
// Per iter: stage -> syncthreads (drain+publish) -> compute -> syncthreads.
// Exposed staging latency is covered by the 4 other resident blocks.
__global__ __launch_bounds__(256, 5) void attn(const bf16* __restrict__ Q,
                                               const bf16* __restrict__ K,
                                               const bf16* __restrict__ Vt,
                                               bf16* __restrict__ O) {
  __shared__ bf16 Ks[128 * 64];      // 16 KB
  __shared__ bf16 Vts[128 * 64];     // 16 KB (2 sub-tiles of [64][64])
  const int tid  = threadIdx.x;
  const int wave = tid >> 6;
  const int lane = tid & 63;
  const int lrow = lane & 15;
  const int quad = lane >> 4;
  const int lin  = blockIdx.x;           // 0..1023
  const int bh   = lin & 31;             // same bh -> same XCD residue (L2)
  const int qi   = 31 - (lin >> 5);      // big q-tiles dispatch first
  const int b = bh >> 4;
  const int h = bh & 15;
  const int qw = qi * 64 + wave * 16;    // wave's q base
  const int nt = (qi + 2) >> 1;          // 128-wide k-tiles (1..16)

  const bf16* Qh  = Q  + (size_t)(b * SEQ) * DIMM + h * HD;
  const bf16* Kh  = K  + (size_t)(b * SEQ) * DIMM + h * HD;
  const bf16* Vth = Vt + (size_t)bh * 64 * SEQ;

  // staging coords: 256 thr cover 32 rows x 128B per pass; swizzled src col
  const int srow = tid >> 3;             // 0..31
  const int sdst = srow * 64 + (tid & 7) * 8;      // LDS dest (elems)
  const int sx   = ((tid & 7) ^ (srow & 7)) * 8;   // (srow+32)&7 == srow&7
  const int cx0 = ((0 + quad) ^ (lrow & 7)) * 8;
  const int cx1 = ((4 + quad) ^ (lrow & 7)) * 8;

  bf16x8 qf0 = *(const bf16x8*)&Qh[(size_t)(qw + lrow) * DIMM + quad * 8];
  bf16x8 qf1 = *(const bf16x8*)&Qh[(size_t)(qw + lrow) * DIMM + 32 + quad * 8];

  const bf16* kg = Kh + (size_t)srow * DIMM + sx;
  const bf16* vg = Vth + (size_t)srow * SEQ + sx;

  f32x4 lacc = {};
  f32x4 o_acc[4] = {};

#pragma unroll 1
  for (int kt = 0; kt < nt; ++kt) {
    // ---- stage tile kt into the single buffer (8 loads/thread) ----
#pragma unroll
    for (int i = 0; i < 4; ++i)
      async16(&Ks[sdst + i * 2048], kg + (size_t)i * 32 * DIMM);
    async16(&Vts[sdst],        vg);
    async16(&Vts[sdst + 2048], vg + (size_t)32 * SEQ);
    async16(&Vts[sdst + 4096], vg + 64);
    async16(&Vts[sdst + 6144], vg + (size_t)32 * SEQ + 64);
    kg += 128 * DIMM; vg += 128;
    __syncthreads();   // drains staging (vmcnt 0) + cross-wave publish
    // ---- S^T = K Q^T from LDS (Q pre-scaled by C1 at qkv) ----
    f32x4 s[8];
#pragma unroll
    for (int gg = 0; gg < 8; ++gg) {
      s[gg] = f32x4{};
      bf16x8 kf0 = *(const bf16x8*)&Ks[(gg * 16 + lrow) * 64 + cx0];
      bf16x8 kf1 = *(const bf16x8*)&Ks[(gg * 16 + lrow) * 64 + cx1];
      s[gg] = __builtin_amdgcn_mfma_f32_16x16x32_bf16(kf0, qf0, s[gg], 0, 0, 0);
      s[gg] = __builtin_amdgcn_mfma_f32_16x16x32_bf16(kf1, qf1, s[gg], 0, 0, 0);
    }
    // ---- causal mask: only the last tile (covers diagonal + overshoot) ----
    if (kt == nt - 1) {
      const int qrow = qw + lrow;
      const int kbase = kt * 128;
#pragma unroll
      for (int gg = 0; gg < 8; ++gg)
#pragma unroll
        for (int r = 0; r < 4; ++r)
          s[gg][r] = (kbase + gg * 16 + quad * 4 + r > qrow) ? -1e30f : s[gg][r];
    }
    // ---- max-free softmax: p = exp2(s); 4 independent sum chains ----
    bf16x8 pf0, pf1, pf2, pf3;           // PV B-fragments, built in-register
#pragma unroll
    for (int gg = 0; gg < 8; ++gg)
#pragma unroll
      for (int r = 0; r < 4; ++r) {
        const float p = __builtin_amdgcn_exp2f(s[gg][r]);
        lacc[r] += p;
        if      (gg < 2) pf0[(gg & 1) * 4 + r] = (bf16)p;
        else if (gg < 4) pf1[(gg & 1) * 4 + r] = (bf16)p;
        else if (gg < 6) pf2[(gg & 1) * 4 + r] = (bf16)p;
        else             pf3[(gg & 1) * 4 + r] = (bf16)p;
      }
    // ---- O^T += Vt P^T ; k-permuted Vt -> contiguous b128 reads ----------
#pragma unroll
    for (int dt = 0; dt < 4; ++dt) {
      const bf16* Vr0 = &Vts[(dt * 16 + lrow) * 64];          // k sub 0
      const bf16* Vr1 = &Vts[4096 + (dt * 16 + lrow) * 64];   // k sub 1
      bf16x8 vA = *(const bf16x8*)&Vr0[cx0];
      bf16x8 vB = *(const bf16x8*)&Vr0[cx1];
      bf16x8 vC = *(const bf16x8*)&Vr1[cx0];
      bf16x8 vD = *(const bf16x8*)&Vr1[cx1];
      o_acc[dt] = __builtin_amdgcn_mfma_f32_16x16x32_bf16(vA, pf0, o_acc[dt], 0, 0, 0);
      o_acc[dt] = __builtin_amdgcn_mfma_f32_16x16x32_bf16(vB, pf1, o_acc[dt], 0, 0, 0);
      o_acc[dt] = __builtin_amdgcn_mfma_f32_16x16x32_bf16(vC, pf2, o_acc[dt], 0, 0, 0);
      o_acc[dt] = __builtin_amdgcn_mfma_f32_16x16x32_bf16(vD, pf3, o_acc[dt], 0, 0, 0);
    }
    __syncthreads();   // all reads done before next iter's re-stage
  }

  // ---- epilogue: cross-lane l reduce (registers only; no LDS) ----
  float lsum = (lacc[0] + lacc[1]) + (lacc[2] + lacc[3]);
  lsum += __shfl_xor(lsum, 16);
  lsum += __shfl_xor(lsum, 32);
  const float rl = __builtin_amdgcn_rcpf(lsum);
  bf16* Ob = O + (size_t)(b * SEQ + qw + lrow) * DIMM + h * HD;
#pragma unroll
  for (int dt = 0; dt < 4; ++dt) {
    bf16x4 ov;
#pragma unroll
    for (int r = 0; r < 4; ++r)
      ov[r] = (bf16)(o_acc[dt][r] * rl);
    *(bf16x4*)&Ob[dt * 16 + quad * 4] = ov;
  }
}

// ---------------- launch ----------------
extern "C" void kernel_launch(void* const* d_in, const int* in_sizes, int n_in,
                              void* d_out, int out_size, void* d_ws, size_t ws_size,
                              hipStream_t stream) {
  const float* x  = (const float*)d_in[0];
  const float* wq = (const float*)d_in[1];
  const float* wk = (const float*)d_in[2];
  const float* wv = (const float*)d_in[3];
  const float* wo = (const float*)d_in[4];

  const size_t M4 = (size_t)MTOT * DIMM;  // 4M elems
  bf16* xb  = (bf16*)d_ws;                // 4M   (reused as CTX after qkv)
  bf16* Wb  = xb + M4;                    // 4M: [wq|wk|wv|wo]
  bf16* Q   = Wb + M4;                    // 4M
  bf16* Kb  = Q + M4;                     // 4M
  bf16* Vt  = Kb + M4;                    // 4M
  bf16* CTX = xb;                         // alias: xb dead after qkv_gemm
  float* out = (float*)d_out;

  convert_all<<<dim3(1024), dim3(256), 0, stream>>>(x, wq, wk, wv, wo, xb, Wb);
  qkv_gemm<<<dim3(512), dim3(256), 0, stream>>>(xb, Wb, Q, Kb, Vt);
  attn<<<dim3(1024), dim3(256), 0, stream>>>(Q, Kb, Vt, CTX);
  proj_gemm<<<dim3(512), dim3(256), 0, stream>>>(CTX, Wb + 3 * 1048576, out);
}